// Round 10
// baseline (68.975 us; speedup 1.0000x reference)
//
#include <hip/hip_runtime.h>
#include <hip/hip_bf16.h>

#define BN 512   // batch
#define DD 512   // feature dim
#define LL 24    // label dim

typedef unsigned short u16;
typedef __attribute__((ext_vector_type(8))) short short8;  // 8 bf16 = 4 VGPR
typedef __attribute__((ext_vector_type(4))) float f32x4;

// ws layout (float words):
//   [0,512)              masks (u32)
//   [512, 512+262144)    Dm (f32, 512x512)
//   [262656]             accum: [0]=sum(f32) [1]=cnt(u32)

__device__ __forceinline__ float dist_val(float d2, bool diag) {
    d2 = fmaxf(d2, 0.0f);
    float d = sqrtf(d2);
    return diag ? 0.0f : d;
}

__device__ __forceinline__ unsigned pk_bf16(float lo, float hi) {
    __hip_bfloat162 p = __float22bfloat162_rn(make_float2(lo, hi));
    unsigned u;
    __builtin_memcpy(&u, &p, 4);     // type-pun; bit_cast rejects non-trivial ctor
    return u;
}

// pack 8 f32 -> bf16 fragment via v_cvt_pk_bf16_f32, accumulate sum of squares
__device__ __forceinline__ short8 pack8_pk(float4 x, float4 y, float& nrm) {
    nrm = fmaf(x.x, x.x, nrm); nrm = fmaf(x.y, x.y, nrm);
    nrm = fmaf(x.z, x.z, nrm); nrm = fmaf(x.w, x.w, nrm);
    nrm = fmaf(y.x, y.x, nrm); nrm = fmaf(y.y, y.y, nrm);
    nrm = fmaf(y.z, y.z, nrm); nrm = fmaf(y.w, y.w, nrm);
    union { uint4 u; short8 s; } cv;
    cv.u.x = pk_bf16(x.x, x.y);
    cv.u.y = pk_bf16(x.z, x.w);
    cv.u.z = pk_bf16(y.x, y.y);
    cv.u.w = pk_bf16(y.z, y.w);
    return cv.s;
}

// ---------- kernel 1: fused prep + bf16 MFMA dist, symmetric (bx>=by only) ---
__global__ __launch_bounds__(64) void dist_fused_kernel(
    const float* __restrict__ S, const int* __restrict__ labels,
    unsigned* __restrict__ masks, float* __restrict__ Dm, float* __restrict__ accum)
{
    const int bx = blockIdx.x, by = blockIdx.y;
    if (bx < by) return;            // D symmetric: upper-triangle tiles only

    const int l    = threadIdx.x;
    const int r    = l & 15;        // fragment row (A.m / B.n), also C.col
    const int half = l >> 4;        // k-base half*8; C.row base half*4
    const int jb = bx * 16;
    const int ib = by * 16;
    const int kb = half * 8;

    // masks (y==0 blocks, 16 rows each; never early-exit) + accum zero (0,0)
    if (by == 0) {
        if (l < 16) {
            const int row = bx * 16 + l;
            const int* lab = labels + row * LL;
            unsigned m = 0;
#pragma unroll
            for (int q = 0; q < LL; q++) m |= (lab[q] != 0 ? 1u : 0u) << q;
            masks[row] = m;
        }
        if (bx == 0 && l == 0) { accum[0] = 0.0f; ((unsigned*)accum)[1] = 0u; }
    }

    const float* pA = S + (size_t)(ib + r) * DD + kb;
    const float* pB = S + (size_t)(jb + r) * DD + kb;

    f32x4 acc = {0.f, 0.f, 0.f, 0.f};
    float nA = 0.f, nB = 0.f;

    float4 ax = *(const float4*)pA, ay = *(const float4*)(pA + 4);
    float4 bx4 = *(const float4*)pB, by4 = *(const float4*)(pB + 4);

    for (int k0 = 0; k0 < DD; k0 += 32) {
        float4 nax, nay, nbx, nby;
        const int kn = k0 + 32;
        if (kn < DD) {              // uniform: prefetch next k-step
            nax = *(const float4*)(pA + kn); nay = *(const float4*)(pA + kn + 4);
            nbx = *(const float4*)(pB + kn); nby = *(const float4*)(pB + kn + 4);
        }
        short8 af = pack8_pk(ax, ay, nA);
        short8 bf = pack8_pk(bx4, by4, nB);
        acc = __builtin_amdgcn_mfma_f32_16x16x32_bf16(af, bf, acc, 0, 0, 0);
        ax = nax; ay = nay; bx4 = nbx; by4 = nby;
    }

    // norms: row ib+r covered by lanes {r, r+16, r+32, r+48} (disjoint k) -> reduce
    nA += __shfl_xor(nA, 16); nA += __shfl_xor(nA, 32);
    nB += __shfl_xor(nB, 16); nB += __shfl_xor(nB, 32);

    // C/D layout (verified R5-R9): col = lane&15, row = half*4 + reg
    const int jc = jb + r;
    const float nj = nB;
    float v[4];
#pragma unroll
    for (int p = 0; p < 4; p++) {
        const int ir = ib + half * 4 + p;
        const float ni = __shfl(nA, half * 4 + p);   // lane (half*4+p) holds row ib+half*4+p
        v[p] = dist_val(ni + nj - 2.f * acc[p], ir == jc);
        Dm[(size_t)ir * BN + jc] = v[p];             // normal layout
    }
    // mirrored tile: Dm[jc][ib+half*4 .. +3] — consecutive, one float4 store
    *(float4*)&Dm[(size_t)jc * BN + ib + half * 4] = make_float4(v[0], v[1], v[2], v[3]);
}

// ---------------- kernel 2: triplet (R4-proven ballot compaction) ------------
__global__ void triplet_kernel(const float* __restrict__ Dm, const unsigned* __restrict__ masks,
                               float* __restrict__ accum) {
    __shared__ float pos[BN];
    __shared__ float neg[BN];
    __shared__ int pcnt, ncnt;
    __shared__ float wsum[4];
    __shared__ unsigned wcnt[4];
    const int i = blockIdx.x;
    const int t = threadIdx.x;          // 256
    const int lane = t & 63;
    const int w = t >> 6;
    if (t == 0) { pcnt = 0; ncnt = 0; }
    __syncthreads();
    const unsigned mi = masks[i];
    const float* drow = Dm + (size_t)i * BN;
    const unsigned long long ltmask = (1ull << lane) - 1ull;

    for (int j = t; j < BN; j += 256) {
        float dj = drow[j];
        bool isp = (mi & masks[j]) != 0u;
        unsigned long long bal = __ballot(isp);
        int np = __popcll(bal);
        if (np > 0) {
            int ldr = __ffsll((unsigned long long)bal) - 1;
            int base = 0;
            if (lane == ldr) base = atomicAdd(&pcnt, np);
            base = __shfl(base, ldr);
            if (isp) pos[base + __popcll(bal & ltmask)] = dj;
        }
        unsigned long long nbal = ~bal;
        int nn = 64 - np;
        if (nn > 0) {
            int ldr = __ffsll((unsigned long long)nbal) - 1;
            int base = 0;
            if (lane == ldr) base = atomicAdd(&ncnt, nn);
            base = __shfl(base, ldr);
            if (!isp) neg[base + __popcll(nbal & ltmask)] = dj;
        }
    }
    __syncthreads();

    const int P = pcnt, N = ncnt;
    float sum = 0.f;
    unsigned cnt = 0;
    for (int p = t; p < P; p += 256) {
        float a = pos[p];
        for (int n = 0; n < N; n++) {
            float v = a - neg[n];
            sum += fmaxf(v, 0.0f);
            cnt += (v > 1e-16f) ? 1u : 0u;
        }
    }
#pragma unroll
    for (int off = 32; off > 0; off >>= 1) {
        sum += __shfl_down(sum, off);
        cnt += __shfl_down(cnt, off);
    }
    if (lane == 0) { wsum[w] = sum; wcnt[w] = cnt; }
    __syncthreads();
    if (t == 0) {
        sum = wsum[0] + wsum[1] + wsum[2] + wsum[3];
        cnt = wcnt[0] + wcnt[1] + wcnt[2] + wcnt[3];
        if (sum != 0.f || cnt != 0u) {
            atomicAdd(&accum[0], sum);
            atomicAdd(&((unsigned*)accum)[1], cnt);
        }
    }
}

// ---------------- kernel 3: finalize -----------------------------------------
__global__ void finalize_kernel(const float* __restrict__ accum, float* __restrict__ out) {
    if (threadIdx.x == 0) {
        float s = accum[0];
        float c = (float)((const unsigned*)accum)[1];
        out[0] = s / (c + 1e-16f);
    }
}

extern "C" void kernel_launch(void* const* d_in, const int* in_sizes, int n_in,
                              void* d_out, int out_size, void* d_ws, size_t ws_size,
                              hipStream_t stream) {
    const float* src    = (const float*)d_in[0];
    const int*   labels = (const int*)d_in[1];
    float* ws = (float*)d_ws;
    unsigned* masks = (unsigned*)ws;
    float*    Dm    = ws + BN;
    float*    accum = ws + BN + (size_t)BN * BN;

    hipLaunchKernelGGL(dist_fused_kernel, dim3(32, 32), dim3(64),  0, stream,
                       src, labels, masks, Dm, accum);
    hipLaunchKernelGGL(triplet_kernel,    dim3(BN),     dim3(256), 0, stream,
                       Dm, masks, accum);
    hipLaunchKernelGGL(finalize_kernel,   dim3(1),      dim3(64),  0, stream,
                       accum, (float*)d_out);
}